// Round 8
// baseline (1360.163 us; speedup 1.0000x reference)
//
#include <hip/hip_runtime.h>

typedef unsigned int u32;
typedef unsigned short u16;

#define ND 50000
#define NF 50000
#define NE 800000
#define DD 64
#define NBLK 196   // ceil(50000/256)
#define EBLK 3125  // 800000/256

// ---- ws float-index layout (8,200,064 floats = 32.8 MB < proven 38.8 MB) ----
#define OFF_FLAGS 0                        // [0] = idx-is-int64
#define OFF_CNTN  64                       // 50000 int
#define OFF_CNTF  (OFF_CNTN + 50000)       // 50000 int
#define OFF_STAN  (OFF_CNTF + 50000)       // 50000 int (after fill: end offsets)
#define OFF_STAF  (OFF_STAN + 50000)       // 50000 int
#define OFF_LISTN (OFF_STAF + 50000)       // 800000 u32
#define OFF_LISTF (OFF_LISTN + 800000)     // 800000 u32
#define OFF_MSGN  (OFF_LISTF + 800000)     // 3.2M f: msg sums; rows later hold NOw bf16
#define OFF_MSGF  (OFF_MSGN + 3200000)     // 3.2M f: msg sums; rows later hold FOw bf16
#define WS_FLOATS (OFF_MSGF + 3200000)

// d_out overlays (strictly ordered across kernel boundaries):
//   node region   [0, 3.2M floats)   : Fp (bf16, half used) -> overwritten by upd-node
//   edge region   [3.2M, 54.4M)      : ep (bf16, half used) -> overwritten by k_eout
//   feature region[54.4M, 57.6M)     : Np (bf16, half used) -> overwritten by upd-feat

__device__ __forceinline__ u16 f2bf(float x){ union{u32 u;float f;}v; v.f=x; u32 r=v.u+0x7fffu+((v.u>>16)&1u); return (u16)(r>>16); }
__device__ __forceinline__ float bf2f(u16 h){ union{u32 u;float f;}v; v.u=((u32)h)<<16; return v.f; }
__device__ __forceinline__ u32 pk2(float a,float b){ return (u32)f2bf(a) | ((u32)f2bf(b)<<16); }

// full-width (64-col) gemv — used only by k_upd
__device__ __forceinline__ void gemv_f32(const float* __restrict__ x,
                                         const float* __restrict__ wt,
                                         float acc[DD]) {
  #pragma unroll 4
  for (int k4 = 0; k4 < 16; ++k4) {
    const float4 v = *(const float4*)(x + k4*4);
    const float f[4] = {v.x, v.y, v.z, v.w};
    const float* __restrict__ wr = wt + k4*4*DD;
    #pragma unroll
    for (int c = 0; c < DD; ++c) {
      float a = acc[c];
      #pragma unroll
      for (int j = 0; j < 4; ++j) a = fmaf(f[j], wr[j*DD + c], a);
      acc[c] = a;
    }
  }
}

// half-width gemv: acc[32] covers cols [0,32) of wt (caller offsets wt by h*32)
__device__ __forceinline__ void gemv_half(const float* __restrict__ x,
                                          const float* __restrict__ wt,
                                          float acc[32]) {
  #pragma unroll 2
  for (int k4 = 0; k4 < 16; ++k4) {
    const float4 v = *(const float4*)(x + k4*4);
    const float f[4] = {v.x, v.y, v.z, v.w};
    const float* __restrict__ wr = wt + k4*4*DD;
    #pragma unroll
    for (int c = 0; c < 32; ++c) {
      float a = acc[c];
      #pragma unroll
      for (int j = 0; j < 4; ++j) a = fmaf(f[j], wr[j*DD + c], a);
      acc[c] = a;
    }
  }
}

__device__ __forceinline__ void gemv_reg(const float x[DD],
                                         const float* __restrict__ wt,
                                         float acc[DD]) {
  #pragma unroll 8
  for (int k = 0; k < DD; ++k) {
    const float fk = x[k];
    const float* __restrict__ wr = wt + k*DD;
    #pragma unroll
    for (int c = 0; c < DD; ++c) acc[c] = fmaf(fk, wr[c], acc[c]);
  }
}

__device__ __forceinline__ void store_row(float* __restrict__ o, const float acc[DD]) {
  float4* o4 = (float4*)o;
  #pragma unroll
  for (int i = 0; i < 16; ++i)
    o4[i] = make_float4(acc[4*i], acc[4*i+1], acc[4*i+2], acc[4*i+3]);
}

__device__ __forceinline__ void store_f_half(float* __restrict__ o, const float acc[32]) {
  float4* o4 = (float4*)o;
  #pragma unroll
  for (int i = 0; i < 8; ++i)
    o4[i] = make_float4(acc[4*i], acc[4*i+1], acc[4*i+2], acc[4*i+3]);
}

// 64 fp32 -> 64 bf16 (128B) row store (used by k_upd)
__device__ __forceinline__ void store_h_row(u16* __restrict__ o, const float acc[DD]) {
  uint4 s[8]; u32* sw = (u32*)s;
  #pragma unroll
  for (int i = 0; i < 32; ++i) sw[i] = pk2(acc[2*i], acc[2*i+1]);
  uint4* o4 = (uint4*)o;
  #pragma unroll
  for (int i = 0; i < 8; ++i) o4[i] = s[i];
}

// 32 fp32 -> 32 bf16 (64B) half-row store
__device__ __forceinline__ void store_h_half(u16* __restrict__ o, const float acc[32]) {
  uint4 s[4]; u32* sw = (u32*)s;
  #pragma unroll
  for (int i = 0; i < 16; ++i) sw[i] = pk2(acc[2*i], acc[2*i+1]);
  uint4* o4 = (uint4*)o;
  #pragma unroll
  for (int i = 0; i < 4; ++i) o4[i] = s[i];
}

// acc[0..31] += bf16halfrow[c]
__device__ __forceinline__ void addrow_h_half(const u16* __restrict__ r, float acc[32]) {
  const uint4* r4 = (const uint4*)r;
  #pragma unroll
  for (int q = 0; q < 4; ++q) {
    const uint4 v = r4[q];
    const u32 w[4] = {v.x, v.y, v.z, v.w};
    #pragma unroll
    for (int h = 0; h < 4; ++h) {
      acc[q*8 + 2*h]     += bf2f((u16)(w[h] & 0xffffu));
      acc[q*8 + 2*h + 1] += bf2f((u16)(w[h] >> 16));
    }
  }
}

// int64 edge_index => every odd u32 word is 0
__global__ __launch_bounds__(256) void k_detect(const u32* __restrict__ idxw,
                                                int* __restrict__ flags) {
  __shared__ int cn;
  if (threadIdx.x == 0) cn = 0;
  __syncthreads();
  int c = 0;
  for (int k = 0; k < 16; ++k)
    c += (idxw[2*(threadIdx.x + k*256) + 1] != 0u) ? 1 : 0;
  atomicAdd(&cn, c);
  __syncthreads();
  if (threadIdx.x == 0) flags[0] = (cn == 0) ? 1 : 0;
}

__global__ __launch_bounds__(256) void k_hist(const u32* __restrict__ eidx,
                                              int* __restrict__ cntN,
                                              int* __restrict__ cntF,
                                              const int* __restrict__ flags) {
  const int e = blockIdx.x*256 + threadIdx.x;
  const int I64 = flags[0];
  const u32 src = I64 ? eidx[2*(size_t)e]        : eidx[e];
  const u32 dst = I64 ? eidx[2*((size_t)NE + e)] : eidx[(size_t)NE + e];
  atomicAdd(cntN + src, 1);
  atomicAdd(cntF + dst, 1);
}

// exclusive prefix sum of 50000 ints; block 0 -> (cntN->staN), block 1 -> (cntF->staF)
__global__ __launch_bounds__(1024) void k_scan(const int* __restrict__ cnt,
                                               int* __restrict__ sta) {
  const int base = blockIdx.x * 50000;
  const int t = threadIdx.x;
  __shared__ int part[1024];
  int local[49];
  int s = 0;
  const int start = t * 49;
  #pragma unroll
  for (int j = 0; j < 49; ++j) {
    const int idx = start + j;
    const int v = (idx < 50000) ? cnt[base + idx] : 0;
    local[j] = s;
    s += v;
  }
  part[t] = s;
  __syncthreads();
  for (int off = 1; off < 1024; off <<= 1) {
    int v = 0;
    if (t >= off) v = part[t - off];
    __syncthreads();
    if (t >= off) part[t] += v;
    __syncthreads();
  }
  const int bv = (t > 0) ? part[t - 1] : 0;
  #pragma unroll
  for (int j = 0; j < 49; ++j) {
    const int idx = start + j;
    if (idx < 50000) sta[base + idx] = bv + local[j];
  }
}

// uses sta as cursors; afterwards sta[n] = end offset
__global__ __launch_bounds__(256) void k_fill(const u32* __restrict__ eidx,
                                              int* __restrict__ staN,
                                              int* __restrict__ staF,
                                              u32* __restrict__ listN,
                                              u32* __restrict__ listF,
                                              const int* __restrict__ flags) {
  const int e = blockIdx.x*256 + threadIdx.x;
  const int I64 = flags[0];
  const u32 src = I64 ? eidx[2*(size_t)e]        : eidx[e];
  const u32 dst = I64 ? eidx[2*((size_t)NE + e)] : eidx[(size_t)NE + e];
  listN[atomicAdd(staN + src, 1)] = (u32)e;
  listF[atomicAdd(staF + dst, 1)] = (u32)e;
}

// proj[row] (bf16) = emb[row] @ wt   — two col-phases, acc[32] each
__global__ __launch_bounds__(256, 6) void k_proj(const float* __restrict__ emb,
                                                 const float* __restrict__ wt,
                                                 u16* __restrict__ outp) {
  const int row = blockIdx.x*256 + threadIdx.x;
  if (row >= 50000) return;
  const float* __restrict__ x = emb + (size_t)row*DD;
  u16* __restrict__ o = outp + (size_t)row*DD;
  #pragma unroll 1
  for (int h = 0; h < 2; ++h) {
    float acc[32];
    #pragma unroll
    for (int c = 0; c < 32; ++c) acc[c] = 0.f;
    gemv_half(x, wt + h*32, acc);
    store_h_half(o + h*32, acc);
  }
}

// ep[e] (bf16) = eemb[e] @ P1 + bP — two col-phases
__global__ __launch_bounds__(256, 6) void k_ep(const float* __restrict__ eemb,
                                               const float* __restrict__ P1,
                                               const float* __restrict__ bP,
                                               u16* __restrict__ ep) {
  const int e = blockIdx.x*256 + threadIdx.x;
  const float* __restrict__ x = eemb + (size_t)e*DD;
  u16* __restrict__ o = ep + (size_t)e*DD;
  #pragma unroll 1
  for (int h = 0; h < 2; ++h) {
    float acc[32];
    #pragma unroll
    for (int c = 0; c < 32; ++c) acc[c] = bP[h*32 + c];
    gemv_half(x, P1 + h*32, acc);
    store_h_half(o + h*32, acc);
  }
}

// one wave per node: msg[n] (fp32) = SUM over incident edges of relu(ep[e] + proj[other])
__global__ __launch_bounds__(256) void k_gather(const u32* __restrict__ list,
                                                const int* __restrict__ sta,
                                                const int* __restrict__ cnt,
                                                const u32* __restrict__ eidx,
                                                const u16* __restrict__ ep,
                                                const u16* __restrict__ proj,
                                                float* __restrict__ msg,
                                                const int* __restrict__ flags,
                                                int otherIsDst) {
  const int n = blockIdx.x*4 + (threadIdx.x >> 6);
  const int lane = threadIdx.x & 63;
  const int I64 = flags[0];
  const int end = sta[n];
  const int c = cnt[n];
  int i = end - c;
  float acc = 0.f;
  u32 e_cur = 0, o_cur = 0;
  if (c > 0) {
    e_cur = list[i];
    const size_t oo = otherIsDst ? ((size_t)NE + e_cur) : (size_t)e_cur;
    o_cur = I64 ? eidx[2*oo] : eidx[oo];
  }
  while (i < end) {
    const u32 e = e_cur, o = o_cur;
    if (i + 1 < end) {
      e_cur = list[i+1];
      const size_t oo = otherIsDst ? ((size_t)NE + e_cur) : (size_t)e_cur;
      o_cur = I64 ? eidx[2*oo] : eidx[oo];
    }
    acc += fmaxf(bf2f(ep[(size_t)e*DD + lane]) + bf2f(proj[(size_t)o*DD + lane]), 0.f);
    ++i;
  }
  msg[(size_t)n*DD + lane] = acc;   // SUM; single division happens in k_upd
}

// out = emb@Q0 + mean_msg@Q1 + bQ ; then (out@Wseg) as bf16 in-place over msg row
__global__ __launch_bounds__(256) void k_upd(const float* __restrict__ emb,
                                             float* msgp,            // aliased in/out
                                             const int* __restrict__ cnt,
                                             const float* __restrict__ Q,
                                             const float* __restrict__ bQ,
                                             const float* __restrict__ Wseg,
                                             float* __restrict__ outp) {
  const int row = blockIdx.x*256 + threadIdx.x;
  if (row >= 50000) return;
  const float inv = 1.f / fmaxf((float)cnt[row], 1.f);
  float m[DD];
  {
    const float4* mp = (const float4*)(msgp + (size_t)row*DD);
    #pragma unroll
    for (int i = 0; i < 16; ++i) {
      const float4 v = mp[i];
      m[4*i] = v.x*inv; m[4*i+1] = v.y*inv; m[4*i+2] = v.z*inv; m[4*i+3] = v.w*inv;
    }
  }
  float acc[DD];
  #pragma unroll
  for (int c = 0; c < DD; ++c) acc[c] = bQ[c];
  gemv_f32(emb + (size_t)row*DD, Q, acc);
  gemv_reg(m, Q + 64*DD, acc);
  store_row(outp + (size_t)row*DD, acc);

  float acc2[DD];
  #pragma unroll
  for (int c = 0; c < DD; ++c) acc2[c] = 0.f;
  gemv_reg(acc, Wseg, acc2);
  // bf16 projection row stored over the START of this thread's own msg row
  store_h_row((u16*)(msgp + (size_t)row*DD), acc2);
}

// fused edge_out = eemb@W0 + bW + NOw[src] + FOw[dst] — two col-phases
__global__ __launch_bounds__(256, 6) void k_eout(const float* __restrict__ eemb,
                                                 const u32* __restrict__ eidx,
                                                 const float* __restrict__ W,
                                                 const float* __restrict__ bW,
                                                 const u16* __restrict__ NOw,  // stride 128 u16/row
                                                 const u16* __restrict__ FOw,
                                                 float* __restrict__ outp,
                                                 const int* __restrict__ flags) {
  const int e = blockIdx.x*256 + threadIdx.x;
  const int I64 = flags[0];
  const u32 src = I64 ? eidx[2*(size_t)e]        : eidx[e];
  const u32 dst = I64 ? eidx[2*((size_t)NE + e)] : eidx[(size_t)NE + e];
  const float* __restrict__ x = eemb + (size_t)e*DD;
  float* __restrict__ o = outp + (size_t)e*DD;
  #pragma unroll 1
  for (int h = 0; h < 2; ++h) {
    float acc[32];
    #pragma unroll
    for (int c = 0; c < 32; ++c) acc[c] = bW[h*32 + c];
    gemv_half(x, W + h*32, acc);
    addrow_h_half(NOw + (size_t)src*128 + h*32, acc);  // bf16 rows at fp32-row offsets
    addrow_h_half(FOw + (size_t)dst*128 + h*32, acc);
    store_f_half(o + h*32, acc);
  }
}

extern "C" void kernel_launch(void* const* d_in, const int* in_sizes, int n_in,
                              void* d_out, int out_size, void* d_ws, size_t ws_size,
                              hipStream_t stream) {
  if (ws_size < (size_t)WS_FLOATS * 4) return;
  const float* node = (const float*)d_in[0];
  const float* eemb = (const float*)d_in[1];
  const float* feat = (const float*)d_in[2];
  const u32*   eidx = (const u32*)d_in[3];
  const float* P  = (const float*)d_in[4];
  const float* bP = (const float*)d_in[5];
  const float* Q  = (const float*)d_in[6];
  const float* bQ = (const float*)d_in[7];
  const float* W  = (const float*)d_in[8];
  const float* bW = (const float*)d_in[9];
  float* wsf = (float*)d_ws;
  int*   wsi = (int*)d_ws;
  float* out = (float*)d_out;

  u16* Fp_h = (u16*)out;                           // node region (bf16, half used)
  u16* ep_h = (u16*)(out + (size_t)ND*DD);         // edge region (bf16, half used)
  u16* Np_h = (u16*)(out + (size_t)(ND + NE)*DD);  // feature region (bf16, half used)
  float* msgN = wsf + OFF_MSGN;
  float* msgF = wsf + OFF_MSGF;

  hipMemsetAsync((void*)(wsi + OFF_CNTN), 0, (size_t)100000 * 4, stream);
  k_detect<<<1, 256, 0, stream>>>(eidx, wsi + OFF_FLAGS);
  k_hist<<<EBLK, 256, 0, stream>>>(eidx, wsi + OFF_CNTN, wsi + OFF_CNTF, wsi + OFF_FLAGS);
  k_scan<<<2, 1024, 0, stream>>>(wsi + OFF_CNTN, wsi + OFF_STAN);
  k_fill<<<EBLK, 256, 0, stream>>>(eidx, wsi + OFF_STAN, wsi + OFF_STAF,
                                   (u32*)(wsi + OFF_LISTN), (u32*)(wsi + OFF_LISTF),
                                   wsi + OFF_FLAGS);
  k_proj<<<NBLK, 256, 0, stream>>>(feat, P, Fp_h);
  k_proj<<<NBLK, 256, 0, stream>>>(node, P, Np_h);
  k_ep<<<EBLK, 256, 0, stream>>>(eemb, P + 64*DD, bP, ep_h);
  k_gather<<<12500, 256, 0, stream>>>((const u32*)(wsi + OFF_LISTN), wsi + OFF_STAN,
                                      wsi + OFF_CNTN, eidx, ep_h, Fp_h, msgN,
                                      wsi + OFF_FLAGS, 1);
  k_gather<<<12500, 256, 0, stream>>>((const u32*)(wsi + OFF_LISTF), wsi + OFF_STAF,
                                      wsi + OFF_CNTF, eidx, ep_h, Np_h, msgF,
                                      wsi + OFF_FLAGS, 0);
  // upd-feat first (overwrites Np region); then upd-node (overwrites Fp region)
  k_upd<<<NBLK, 256, 0, stream>>>(feat, msgF, wsi + OFF_CNTF, Q, bQ, W + 128*DD,
                                  out + (size_t)(ND + NE)*DD);
  k_upd<<<NBLK, 256, 0, stream>>>(node, msgN, wsi + OFF_CNTN, Q, bQ, W + 64*DD, out);
  // fused edge_out overwrites ep region
  k_eout<<<EBLK, 256, 0, stream>>>(eemb, eidx, W, bW,
                                   (const u16*)msgN, (const u16*)msgF,
                                   out + (size_t)ND*DD, wsi + OFF_FLAGS);
}

// Round 9
// 1183.798 us; speedup vs baseline: 1.1490x; 1.1490x over previous
//
#include <hip/hip_runtime.h>

typedef unsigned int u32;
typedef unsigned short u16;

#define ND 50000
#define NF 50000
#define NE 800000
#define DD 64
#define NBLK 196   // ceil(50000/256)
#define EBLK 3125  // 800000/256

// ---- ws float-index layout (8,200,064 floats = 32.8 MB < proven 38.8 MB) ----
#define OFF_FLAGS 0                        // [0] = idx-is-int64
#define OFF_CNTN  64                       // 50000 int
#define OFF_CNTF  (OFF_CNTN + 50000)       // 50000 int
#define OFF_STAN  (OFF_CNTF + 50000)       // 50000 int (after fill: end offsets)
#define OFF_STAF  (OFF_STAN + 50000)       // 50000 int
#define OFF_LISTN (OFF_STAF + 50000)       // 800000 u32
#define OFF_LISTF (OFF_LISTN + 800000)     // 800000 u32
#define OFF_MSGN  (OFF_LISTF + 800000)     // 3.2M f: msg sums; rows later hold NOw bf16
#define OFF_MSGF  (OFF_MSGN + 3200000)     // 3.2M f: msg sums; rows later hold FOw bf16
#define WS_FLOATS (OFF_MSGF + 3200000)

// d_out overlays (strictly ordered across kernel boundaries):
//   node region   [0, 3.2M floats)   : Fp (bf16, half used) -> overwritten by upd-node
//   edge region   [3.2M, 54.4M)      : ep (bf16, half used) -> overwritten by k_eout
//   feature region[54.4M, 57.6M)     : Np (bf16, half used) -> overwritten by upd-feat

__device__ __forceinline__ u16 f2bf(float x){ union{u32 u;float f;}v; v.f=x; u32 r=v.u+0x7fffu+((v.u>>16)&1u); return (u16)(r>>16); }
__device__ __forceinline__ float bf2f(u16 h){ union{u32 u;float f;}v; v.u=((u32)h)<<16; return v.f; }
__device__ __forceinline__ u32 pk2(float a,float b){ return (u32)f2bf(a) | ((u32)f2bf(b)<<16); }

// full-width (64-col) gemv from global — used only by k_upd (round-7 proven)
__device__ __forceinline__ void gemv_f32(const float* __restrict__ x,
                                         const float* __restrict__ wt,
                                         float acc[DD]) {
  #pragma unroll 4
  for (int k4 = 0; k4 < 16; ++k4) {
    const float4 v = *(const float4*)(x + k4*4);
    const float f[4] = {v.x, v.y, v.z, v.w};
    const float* __restrict__ wr = wt + k4*4*DD;
    #pragma unroll
    for (int c = 0; c < DD; ++c) {
      float a = acc[c];
      #pragma unroll
      for (int j = 0; j < 4; ++j) a = fmaf(f[j], wr[j*DD + c], a);
      acc[c] = a;
    }
  }
}

// register-input gemv; k ascending — same summation order as gemv_f32
__device__ __forceinline__ void gemv_reg(const float x[DD],
                                         const float* __restrict__ wt,
                                         float acc[DD]) {
  #pragma unroll 8
  for (int k = 0; k < DD; ++k) {
    const float fk = x[k];
    const float* __restrict__ wr = wt + k*DD;
    #pragma unroll
    for (int c = 0; c < DD; ++c) acc[c] = fmaf(fk, wr[c], acc[c]);
  }
}

// stage a full 256B row into registers: 16 independent float4 loads (max MLP)
__device__ __forceinline__ void load_row16(const float* __restrict__ x, float xs[DD]) {
  const float4* xp = (const float4*)x;
  #pragma unroll
  for (int i = 0; i < 16; ++i) {
    const float4 v = xp[i];
    xs[4*i] = v.x; xs[4*i+1] = v.y; xs[4*i+2] = v.z; xs[4*i+3] = v.w;
  }
}

__device__ __forceinline__ void store_row(float* __restrict__ o, const float acc[DD]) {
  float4* o4 = (float4*)o;
  #pragma unroll
  for (int i = 0; i < 16; ++i)
    o4[i] = make_float4(acc[4*i], acc[4*i+1], acc[4*i+2], acc[4*i+3]);
}

// 64 fp32 -> 64 bf16 (128B) row store
__device__ __forceinline__ void store_h_row(u16* __restrict__ o, const float acc[DD]) {
  uint4 s[8]; u32* sw = (u32*)s;
  #pragma unroll
  for (int i = 0; i < 32; ++i) sw[i] = pk2(acc[2*i], acc[2*i+1]);
  uint4* o4 = (uint4*)o;
  #pragma unroll
  for (int i = 0; i < 8; ++i) o4[i] = s[i];
}

// acc[c] += bf16row[c]   (full 128B row)
__device__ __forceinline__ void addrow_h(const u16* __restrict__ r, float acc[DD]) {
  const uint4* r4 = (const uint4*)r;
  #pragma unroll
  for (int q = 0; q < 8; ++q) {
    const uint4 v = r4[q];
    const u32 w[4] = {v.x, v.y, v.z, v.w};
    #pragma unroll
    for (int h = 0; h < 4; ++h) {
      acc[q*8 + 2*h]     += bf2f((u16)(w[h] & 0xffffu));
      acc[q*8 + 2*h + 1] += bf2f((u16)(w[h] >> 16));
    }
  }
}

// int64 edge_index => every odd u32 word is 0
__global__ __launch_bounds__(256) void k_detect(const u32* __restrict__ idxw,
                                                int* __restrict__ flags) {
  __shared__ int cn;
  if (threadIdx.x == 0) cn = 0;
  __syncthreads();
  int c = 0;
  for (int k = 0; k < 16; ++k)
    c += (idxw[2*(threadIdx.x + k*256) + 1] != 0u) ? 1 : 0;
  atomicAdd(&cn, c);
  __syncthreads();
  if (threadIdx.x == 0) flags[0] = (cn == 0) ? 1 : 0;
}

__global__ __launch_bounds__(256) void k_hist(const u32* __restrict__ eidx,
                                              int* __restrict__ cntN,
                                              int* __restrict__ cntF,
                                              const int* __restrict__ flags) {
  const int e = blockIdx.x*256 + threadIdx.x;
  const int I64 = flags[0];
  const u32 src = I64 ? eidx[2*(size_t)e]        : eidx[e];
  const u32 dst = I64 ? eidx[2*((size_t)NE + e)] : eidx[(size_t)NE + e];
  atomicAdd(cntN + src, 1);
  atomicAdd(cntF + dst, 1);
}

// exclusive prefix sum of 50000 ints; block 0 -> (cntN->staN), block 1 -> (cntF->staF)
__global__ __launch_bounds__(1024) void k_scan(const int* __restrict__ cnt,
                                               int* __restrict__ sta) {
  const int base = blockIdx.x * 50000;
  const int t = threadIdx.x;
  __shared__ int part[1024];
  int local[49];
  int s = 0;
  const int start = t * 49;
  #pragma unroll
  for (int j = 0; j < 49; ++j) {
    const int idx = start + j;
    const int v = (idx < 50000) ? cnt[base + idx] : 0;
    local[j] = s;
    s += v;
  }
  part[t] = s;
  __syncthreads();
  for (int off = 1; off < 1024; off <<= 1) {
    int v = 0;
    if (t >= off) v = part[t - off];
    __syncthreads();
    if (t >= off) part[t] += v;
    __syncthreads();
  }
  const int bv = (t > 0) ? part[t - 1] : 0;
  #pragma unroll
  for (int j = 0; j < 49; ++j) {
    const int idx = start + j;
    if (idx < 50000) sta[base + idx] = bv + local[j];
  }
}

// uses sta as cursors; afterwards sta[n] = end offset
__global__ __launch_bounds__(256) void k_fill(const u32* __restrict__ eidx,
                                              int* __restrict__ staN,
                                              int* __restrict__ staF,
                                              u32* __restrict__ listN,
                                              u32* __restrict__ listF,
                                              const int* __restrict__ flags) {
  const int e = blockIdx.x*256 + threadIdx.x;
  const int I64 = flags[0];
  const u32 src = I64 ? eidx[2*(size_t)e]        : eidx[e];
  const u32 dst = I64 ? eidx[2*((size_t)NE + e)] : eidx[(size_t)NE + e];
  listN[atomicAdd(staN + src, 1)] = (u32)e;
  listF[atomicAdd(staF + dst, 1)] = (u32)e;
}

// proj[row] (bf16) = emb[row] @ wt — row staged in regs (16 loads in flight)
__global__ __launch_bounds__(256) void k_proj(const float* __restrict__ emb,
                                              const float* __restrict__ wt,
                                              u16* __restrict__ outp) {
  const int row = blockIdx.x*256 + threadIdx.x;
  if (row >= 50000) return;
  float xs[DD];
  load_row16(emb + (size_t)row*DD, xs);
  float acc[DD];
  #pragma unroll
  for (int c = 0; c < DD; ++c) acc[c] = 0.f;
  gemv_reg(xs, wt, acc);
  store_h_row(outp + (size_t)row*DD, acc);
}

// ep[e] (bf16) = eemb[e] @ P1 + bP — row staged in regs
__global__ __launch_bounds__(256) void k_ep(const float* __restrict__ eemb,
                                            const float* __restrict__ P1,
                                            const float* __restrict__ bP,
                                            u16* __restrict__ ep) {
  const int e = blockIdx.x*256 + threadIdx.x;
  float xs[DD];
  load_row16(eemb + (size_t)e*DD, xs);
  float acc[DD];
  #pragma unroll
  for (int c = 0; c < DD; ++c) acc[c] = bP[c];
  gemv_reg(xs, P1, acc);
  store_h_row(ep + (size_t)e*DD, acc);
}

// one wave per node: msg[n] (fp32) = SUM over incident edges of relu(ep[e] + proj[other])
__global__ __launch_bounds__(256) void k_gather(const u32* __restrict__ list,
                                                const int* __restrict__ sta,
                                                const int* __restrict__ cnt,
                                                const u32* __restrict__ eidx,
                                                const u16* __restrict__ ep,
                                                const u16* __restrict__ proj,
                                                float* __restrict__ msg,
                                                const int* __restrict__ flags,
                                                int otherIsDst) {
  const int n = blockIdx.x*4 + (threadIdx.x >> 6);
  const int lane = threadIdx.x & 63;
  const int I64 = flags[0];
  const int end = sta[n];
  const int c = cnt[n];
  int i = end - c;
  float acc = 0.f;
  u32 e_cur = 0, o_cur = 0;
  if (c > 0) {
    e_cur = list[i];
    const size_t oo = otherIsDst ? ((size_t)NE + e_cur) : (size_t)e_cur;
    o_cur = I64 ? eidx[2*oo] : eidx[oo];
  }
  while (i < end) {
    const u32 e = e_cur, o = o_cur;
    if (i + 1 < end) {
      e_cur = list[i+1];
      const size_t oo = otherIsDst ? ((size_t)NE + e_cur) : (size_t)e_cur;
      o_cur = I64 ? eidx[2*oo] : eidx[oo];
    }
    acc += fmaxf(bf2f(ep[(size_t)e*DD + lane]) + bf2f(proj[(size_t)o*DD + lane]), 0.f);
    ++i;
  }
  msg[(size_t)n*DD + lane] = acc;   // SUM; single division happens in k_upd
}

// out = emb@Q0 + mean_msg@Q1 + bQ ; then (out@Wseg) as bf16 in-place over msg row
__global__ __launch_bounds__(256) void k_upd(const float* __restrict__ emb,
                                             float* msgp,            // aliased in/out
                                             const int* __restrict__ cnt,
                                             const float* __restrict__ Q,
                                             const float* __restrict__ bQ,
                                             const float* __restrict__ Wseg,
                                             float* __restrict__ outp) {
  const int row = blockIdx.x*256 + threadIdx.x;
  if (row >= 50000) return;
  const float inv = 1.f / fmaxf((float)cnt[row], 1.f);
  float m[DD];
  {
    const float4* mp = (const float4*)(msgp + (size_t)row*DD);
    #pragma unroll
    for (int i = 0; i < 16; ++i) {
      const float4 v = mp[i];
      m[4*i] = v.x*inv; m[4*i+1] = v.y*inv; m[4*i+2] = v.z*inv; m[4*i+3] = v.w*inv;
    }
  }
  float acc[DD];
  #pragma unroll
  for (int c = 0; c < DD; ++c) acc[c] = bQ[c];
  gemv_f32(emb + (size_t)row*DD, Q, acc);
  gemv_reg(m, Q + 64*DD, acc);
  store_row(outp + (size_t)row*DD, acc);

  float acc2[DD];
  #pragma unroll
  for (int c = 0; c < DD; ++c) acc2[c] = 0.f;
  gemv_reg(acc, Wseg, acc2);
  // bf16 projection row stored over the START of this thread's own msg row
  store_h_row((u16*)(msgp + (size_t)row*DD), acc2);
}

// fused edge_out = eemb@W0 + bW + NOw[src] + FOw[dst] — row staged in regs,
// bf16 gather rows added after the fma loop (round-7 proven placement)
__global__ __launch_bounds__(256) void k_eout(const float* __restrict__ eemb,
                                              const u32* __restrict__ eidx,
                                              const float* __restrict__ W,
                                              const float* __restrict__ bW,
                                              const u16* __restrict__ NOw,  // stride 128 u16/row
                                              const u16* __restrict__ FOw,
                                              float* __restrict__ outp,
                                              const int* __restrict__ flags) {
  const int e = blockIdx.x*256 + threadIdx.x;
  const int I64 = flags[0];
  const u32 src = I64 ? eidx[2*(size_t)e]        : eidx[e];
  const u32 dst = I64 ? eidx[2*((size_t)NE + e)] : eidx[(size_t)NE + e];
  float xs[DD];
  load_row16(eemb + (size_t)e*DD, xs);
  float acc[DD];
  #pragma unroll
  for (int c = 0; c < DD; ++c) acc[c] = bW[c];
  gemv_reg(xs, W, acc);
  addrow_h(NOw + (size_t)src*128, acc);   // bf16 rows live at fp32-row offsets
  addrow_h(FOw + (size_t)dst*128, acc);
  store_row(outp + (size_t)e*DD, acc);
}

extern "C" void kernel_launch(void* const* d_in, const int* in_sizes, int n_in,
                              void* d_out, int out_size, void* d_ws, size_t ws_size,
                              hipStream_t stream) {
  if (ws_size < (size_t)WS_FLOATS * 4) return;
  const float* node = (const float*)d_in[0];
  const float* eemb = (const float*)d_in[1];
  const float* feat = (const float*)d_in[2];
  const u32*   eidx = (const u32*)d_in[3];
  const float* P  = (const float*)d_in[4];
  const float* bP = (const float*)d_in[5];
  const float* Q  = (const float*)d_in[6];
  const float* bQ = (const float*)d_in[7];
  const float* W  = (const float*)d_in[8];
  const float* bW = (const float*)d_in[9];
  float* wsf = (float*)d_ws;
  int*   wsi = (int*)d_ws;
  float* out = (float*)d_out;

  u16* Fp_h = (u16*)out;                           // node region (bf16, half used)
  u16* ep_h = (u16*)(out + (size_t)ND*DD);         // edge region (bf16, half used)
  u16* Np_h = (u16*)(out + (size_t)(ND + NE)*DD);  // feature region (bf16, half used)
  float* msgN = wsf + OFF_MSGN;
  float* msgF = wsf + OFF_MSGF;

  hipMemsetAsync((void*)(wsi + OFF_CNTN), 0, (size_t)100000 * 4, stream);
  k_detect<<<1, 256, 0, stream>>>(eidx, wsi + OFF_FLAGS);
  k_hist<<<EBLK, 256, 0, stream>>>(eidx, wsi + OFF_CNTN, wsi + OFF_CNTF, wsi + OFF_FLAGS);
  k_scan<<<2, 1024, 0, stream>>>(wsi + OFF_CNTN, wsi + OFF_STAN);
  k_fill<<<EBLK, 256, 0, stream>>>(eidx, wsi + OFF_STAN, wsi + OFF_STAF,
                                   (u32*)(wsi + OFF_LISTN), (u32*)(wsi + OFF_LISTF),
                                   wsi + OFF_FLAGS);
  k_proj<<<NBLK, 256, 0, stream>>>(feat, P, Fp_h);
  k_proj<<<NBLK, 256, 0, stream>>>(node, P, Np_h);
  k_ep<<<EBLK, 256, 0, stream>>>(eemb, P + 64*DD, bP, ep_h);
  k_gather<<<12500, 256, 0, stream>>>((const u32*)(wsi + OFF_LISTN), wsi + OFF_STAN,
                                      wsi + OFF_CNTN, eidx, ep_h, Fp_h, msgN,
                                      wsi + OFF_FLAGS, 1);
  k_gather<<<12500, 256, 0, stream>>>((const u32*)(wsi + OFF_LISTF), wsi + OFF_STAF,
                                      wsi + OFF_CNTF, eidx, ep_h, Np_h, msgF,
                                      wsi + OFF_FLAGS, 0);
  // upd-feat first (overwrites Np region); then upd-node (overwrites Fp region)
  k_upd<<<NBLK, 256, 0, stream>>>(feat, msgF, wsi + OFF_CNTF, Q, bQ, W + 128*DD,
                                  out + (size_t)(ND + NE)*DD);
  k_upd<<<NBLK, 256, 0, stream>>>(node, msgN, wsi + OFF_CNTN, Q, bQ, W + 64*DD, out);
  // fused edge_out overwrites ep region
  k_eout<<<EBLK, 256, 0, stream>>>(eemb, eidx, W, bW,
                                   (const u16*)msgN, (const u16*)msgF,
                                   out + (size_t)ND*DD, wsi + OFF_FLAGS);
}

// Round 10
// 1030.933 us; speedup vs baseline: 1.3194x; 1.1483x over previous
//
#include <hip/hip_runtime.h>

typedef unsigned int u32;
typedef unsigned short u16;

#define ND 50000
#define NF 50000
#define NE 800000
#define DD 64
#define NBLK 196   // ceil(50000/256)
#define EBLK 3125  // 800000/256

// ---- ws float-index layout (8,200,064 floats = 32.8 MB < proven 38.9 MB) ----
#define OFF_FLAGS 0                        // [0] = idx-is-int64
#define OFF_CNTN  64                       // 50000 int
#define OFF_CNTF  (OFF_CNTN + 50000)       // 50000 int
#define OFF_STAN  (OFF_CNTF + 50000)       // 50000 int (after fill: end offsets)
#define OFF_STAF  (OFF_STAN + 50000)       // 50000 int
#define OFF_OTHN  (OFF_STAF + 50000)       // 800000 int: dst of edge at CSR slot i (N side)
#define OFF_OTHF  (OFF_OTHN + 800000)      // 800000 int: src of edge at CSR slot i (F side)
#define OFF_MSGN  (OFF_OTHF + 800000)      // 3.2M f: msg sums; first 1.6M floats hold posN/posF
                                           //   during fill->ep (dead before gatherN writes msgN)
#define OFF_MSGF  (OFF_MSGN + 3200000)     // 3.2M f: msg sums; rows later hold FOw bf16
#define WS_FLOATS (OFF_MSGF + 3200000)

// d_out overlays (strictly ordered across kernel boundaries):
//   node region   [0, 3.2M floats)     : Fp bf16 -> overwritten by upd-node
//   edge region   [3.2M, 28.8M floats) : epN bf16 (CSR-sorted, N side) -> overwritten by k_eout
//                 [28.8M, 54.4M)       : epF bf16 (CSR-sorted, F side) -> overwritten by k_eout
//   feature region[54.4M, 57.6M)       : Np bf16 -> overwritten by upd-feat

__device__ __forceinline__ u16 f2bf(float x){ union{u32 u;float f;}v; v.f=x; u32 r=v.u+0x7fffu+((v.u>>16)&1u); return (u16)(r>>16); }
__device__ __forceinline__ float bf2f(u16 h){ union{u32 u;float f;}v; v.u=((u32)h)<<16; return v.f; }
__device__ __forceinline__ u32 pk2(float a,float b){ return (u32)f2bf(a) | ((u32)f2bf(b)<<16); }

// full-width (64-col) gemv from global — round-7 proven (52 VGPR, no spill)
__device__ __forceinline__ void gemv_f32(const float* __restrict__ x,
                                         const float* __restrict__ wt,
                                         float acc[DD]) {
  #pragma unroll 4
  for (int k4 = 0; k4 < 16; ++k4) {
    const float4 v = *(const float4*)(x + k4*4);
    const float f[4] = {v.x, v.y, v.z, v.w};
    const float* __restrict__ wr = wt + k4*4*DD;
    #pragma unroll
    for (int c = 0; c < DD; ++c) {
      float a = acc[c];
      #pragma unroll
      for (int j = 0; j < 4; ++j) a = fmaf(f[j], wr[j*DD + c], a);
      acc[c] = a;
    }
  }
}

// register-input gemv; k ascending — same summation order as gemv_f32
__device__ __forceinline__ void gemv_reg(const float x[DD],
                                         const float* __restrict__ wt,
                                         float acc[DD]) {
  #pragma unroll 8
  for (int k = 0; k < DD; ++k) {
    const float fk = x[k];
    const float* __restrict__ wr = wt + k*DD;
    #pragma unroll
    for (int c = 0; c < DD; ++c) acc[c] = fmaf(fk, wr[c], acc[c]);
  }
}

__device__ __forceinline__ void store_row(float* __restrict__ o, const float acc[DD]) {
  float4* o4 = (float4*)o;
  #pragma unroll
  for (int i = 0; i < 16; ++i)
    o4[i] = make_float4(acc[4*i], acc[4*i+1], acc[4*i+2], acc[4*i+3]);
}

// 64 fp32 -> 64 bf16 (128B) contiguous row store
__device__ __forceinline__ void store_h_row(u16* __restrict__ o, const float acc[DD]) {
  uint4 s[8]; u32* sw = (u32*)s;
  #pragma unroll
  for (int i = 0; i < 32; ++i) sw[i] = pk2(acc[2*i], acc[2*i+1]);
  uint4* o4 = (uint4*)o;
  #pragma unroll
  for (int i = 0; i < 8; ++i) o4[i] = s[i];
}

// acc[c] += bf16row[c]   (full 128B row)
__device__ __forceinline__ void addrow_h(const u16* __restrict__ r, float acc[DD]) {
  const uint4* r4 = (const uint4*)r;
  #pragma unroll
  for (int q = 0; q < 8; ++q) {
    const uint4 v = r4[q];
    const u32 w[4] = {v.x, v.y, v.z, v.w};
    #pragma unroll
    for (int h = 0; h < 4; ++h) {
      acc[q*8 + 2*h]     += bf2f((u16)(w[h] & 0xffffu));
      acc[q*8 + 2*h + 1] += bf2f((u16)(w[h] >> 16));
    }
  }
}

// int64 edge_index => every odd u32 word is 0
__global__ __launch_bounds__(256) void k_detect(const u32* __restrict__ idxw,
                                                int* __restrict__ flags) {
  __shared__ int cn;
  if (threadIdx.x == 0) cn = 0;
  __syncthreads();
  int c = 0;
  for (int k = 0; k < 16; ++k)
    c += (idxw[2*(threadIdx.x + k*256) + 1] != 0u) ? 1 : 0;
  atomicAdd(&cn, c);
  __syncthreads();
  if (threadIdx.x == 0) flags[0] = (cn == 0) ? 1 : 0;
}

__global__ __launch_bounds__(256) void k_hist(const u32* __restrict__ eidx,
                                              int* __restrict__ cntN,
                                              int* __restrict__ cntF,
                                              const int* __restrict__ flags) {
  const int e = blockIdx.x*256 + threadIdx.x;
  const int I64 = flags[0];
  const u32 src = I64 ? eidx[2*(size_t)e]        : eidx[e];
  const u32 dst = I64 ? eidx[2*((size_t)NE + e)] : eidx[(size_t)NE + e];
  atomicAdd(cntN + src, 1);
  atomicAdd(cntF + dst, 1);
}

// exclusive prefix sum of 50000 ints; block 0 -> (cntN->staN), block 1 -> (cntF->staF)
__global__ __launch_bounds__(1024) void k_scan(const int* __restrict__ cnt,
                                               int* __restrict__ sta) {
  const int base = blockIdx.x * 50000;
  const int t = threadIdx.x;
  __shared__ int part[1024];
  int local[49];
  int s = 0;
  const int start = t * 49;
  #pragma unroll
  for (int j = 0; j < 49; ++j) {
    const int idx = start + j;
    const int v = (idx < 50000) ? cnt[base + idx] : 0;
    local[j] = s;
    s += v;
  }
  part[t] = s;
  __syncthreads();
  for (int off = 1; off < 1024; off <<= 1) {
    int v = 0;
    if (t >= off) v = part[t - off];
    __syncthreads();
    if (t >= off) part[t] += v;
    __syncthreads();
  }
  const int bv = (t > 0) ? part[t - 1] : 0;
  #pragma unroll
  for (int j = 0; j < 49; ++j) {
    const int idx = start + j;
    if (idx < 50000) sta[base + idx] = bv + local[j];
  }
}

// CSR fill; also records each edge's slot (pos) and the gather-side node (oth)
__global__ __launch_bounds__(256) void k_fill(const u32* __restrict__ eidx,
                                              int* __restrict__ staN,
                                              int* __restrict__ staF,
                                              int* __restrict__ othN,
                                              int* __restrict__ othF,
                                              int* __restrict__ posN,
                                              int* __restrict__ posF,
                                              const int* __restrict__ flags) {
  const int e = blockIdx.x*256 + threadIdx.x;
  const int I64 = flags[0];
  const u32 src = I64 ? eidx[2*(size_t)e]        : eidx[e];
  const u32 dst = I64 ? eidx[2*((size_t)NE + e)] : eidx[(size_t)NE + e];
  const int pN = atomicAdd(staN + src, 1);
  const int pF = atomicAdd(staF + dst, 1);
  othN[pN] = (int)dst;
  othF[pF] = (int)src;
  posN[e] = pN;
  posF[e] = pF;
}

// proj[row] (bf16) = emb[row] @ wt    (wt = P[:64])
__global__ __launch_bounds__(256) void k_proj(const float* __restrict__ emb,
                                              const float* __restrict__ wt,
                                              u16* __restrict__ outp) {
  const int row = blockIdx.x*256 + threadIdx.x;
  if (row >= 50000) return;
  float acc[DD];
  #pragma unroll
  for (int c = 0; c < DD; ++c) acc[c] = 0.f;
  gemv_f32(emb + (size_t)row*DD, wt, acc);
  store_h_row(outp + (size_t)row*DD, acc);
}

// ep row = eemb[e] @ P1 + bP, written TWICE in CSR-sorted order (scattered stores)
__global__ __launch_bounds__(256) void k_ep(const float* __restrict__ eemb,
                                            const float* __restrict__ P1,
                                            const float* __restrict__ bP,
                                            const int* __restrict__ posN,
                                            const int* __restrict__ posF,
                                            u16* __restrict__ epN,
                                            u16* __restrict__ epF) {
  const int e = blockIdx.x*256 + threadIdx.x;
  float acc[DD];
  #pragma unroll
  for (int c = 0; c < DD; ++c) acc[c] = bP[c];
  gemv_f32(eemb + (size_t)e*DD, P1, acc);
  store_h_row(epN + (size_t)posN[e]*DD, acc);
  store_h_row(epF + (size_t)posF[e]*DD, acc);
}

// one wave per node: msg[n] = SUM over CSR range of relu(eps[i] + proj[oth[i]])
// eps is CSR-sorted -> purely sequential reads; oth is wave-uniform -> s_load.
__global__ __launch_bounds__(256) void k_gather2(const int* __restrict__ sta,
                                                 const int* __restrict__ cnt,
                                                 const int* __restrict__ oth,
                                                 const u16* __restrict__ eps,
                                                 const u16* __restrict__ proj,
                                                 float* __restrict__ msg) {
  const int n = blockIdx.x*4 + (threadIdx.x >> 6);
  const int lane = threadIdx.x & 63;
  const int end = sta[n];
  const int c = cnt[n];
  float acc = 0.f;
  #pragma unroll 4
  for (int i = end - c; i < end; ++i) {
    const int o = oth[i];
    acc += fmaxf(bf2f(eps[(size_t)i*DD + lane]) + bf2f(proj[(size_t)o*DD + lane]), 0.f);
  }
  msg[(size_t)n*DD + lane] = acc;   // SUM; single division happens in k_upd
}

// out = emb@Q0 + mean_msg@Q1 + bQ ; then (out@Wseg) as bf16 in-place over msg row
__global__ __launch_bounds__(256) void k_upd(const float* __restrict__ emb,
                                             float* msgp,            // aliased in/out
                                             const int* __restrict__ cnt,
                                             const float* __restrict__ Q,
                                             const float* __restrict__ bQ,
                                             const float* __restrict__ Wseg,
                                             float* __restrict__ outp) {
  const int row = blockIdx.x*256 + threadIdx.x;
  if (row >= 50000) return;
  const float inv = 1.f / fmaxf((float)cnt[row], 1.f);
  float m[DD];
  {
    const float4* mp = (const float4*)(msgp + (size_t)row*DD);
    #pragma unroll
    for (int i = 0; i < 16; ++i) {
      const float4 v = mp[i];
      m[4*i] = v.x*inv; m[4*i+1] = v.y*inv; m[4*i+2] = v.z*inv; m[4*i+3] = v.w*inv;
    }
  }
  float acc[DD];
  #pragma unroll
  for (int c = 0; c < DD; ++c) acc[c] = bQ[c];
  gemv_f32(emb + (size_t)row*DD, Q, acc);
  gemv_reg(m, Q + 64*DD, acc);
  store_row(outp + (size_t)row*DD, acc);

  float acc2[DD];
  #pragma unroll
  for (int c = 0; c < DD; ++c) acc2[c] = 0.f;
  gemv_reg(acc, Wseg, acc2);
  // bf16 projection row stored over the START of this thread's own msg row
  store_h_row((u16*)(msgp + (size_t)row*DD), acc2);
}

// fused edge_out = eemb@W0 + bW + NOw[src] + FOw[dst]  (round-7 proven)
__global__ __launch_bounds__(256) void k_eout(const float* __restrict__ eemb,
                                              const u32* __restrict__ eidx,
                                              const float* __restrict__ W,
                                              const float* __restrict__ bW,
                                              const u16* __restrict__ NOw,  // stride 128 u16/row
                                              const u16* __restrict__ FOw,
                                              float* __restrict__ outp,
                                              const int* __restrict__ flags) {
  const int e = blockIdx.x*256 + threadIdx.x;
  const int I64 = flags[0];
  const u32 src = I64 ? eidx[2*(size_t)e]        : eidx[e];
  const u32 dst = I64 ? eidx[2*((size_t)NE + e)] : eidx[(size_t)NE + e];
  float acc[DD];
  #pragma unroll
  for (int c = 0; c < DD; ++c) acc[c] = bW[c];
  gemv_f32(eemb + (size_t)e*DD, W, acc);
  addrow_h(NOw + (size_t)src*128, acc);   // bf16 rows live at fp32-row offsets
  addrow_h(FOw + (size_t)dst*128, acc);
  store_row(outp + (size_t)e*DD, acc);
}

extern "C" void kernel_launch(void* const* d_in, const int* in_sizes, int n_in,
                              void* d_out, int out_size, void* d_ws, size_t ws_size,
                              hipStream_t stream) {
  if (ws_size < (size_t)WS_FLOATS * 4) return;
  const float* node = (const float*)d_in[0];
  const float* eemb = (const float*)d_in[1];
  const float* feat = (const float*)d_in[2];
  const u32*   eidx = (const u32*)d_in[3];
  const float* P  = (const float*)d_in[4];
  const float* bP = (const float*)d_in[5];
  const float* Q  = (const float*)d_in[6];
  const float* bQ = (const float*)d_in[7];
  const float* W  = (const float*)d_in[8];
  const float* bW = (const float*)d_in[9];
  float* wsf = (float*)d_ws;
  int*   wsi = (int*)d_ws;
  float* out = (float*)d_out;

  u16* Fp_h = (u16*)out;                           // node region (bf16, half used)
  u16* epN_h = (u16*)(out + (size_t)ND*DD);        // edge region: CSR-sorted ep (N side)
  u16* epF_h = epN_h + (size_t)NE*DD;              // edge region: CSR-sorted ep (F side)
  u16* Np_h = (u16*)(out + (size_t)(ND + NE)*DD);  // feature region (bf16, half used)
  float* msgN = wsf + OFF_MSGN;
  float* msgF = wsf + OFF_MSGF;
  int* posN = (int*)(wsf + OFF_MSGN);              // overlays msgN start; dead after k_ep
  int* posF = posN + NE;

  hipMemsetAsync((void*)(wsi + OFF_CNTN), 0, (size_t)100000 * 4, stream);
  k_detect<<<1, 256, 0, stream>>>(eidx, wsi + OFF_FLAGS);
  k_hist<<<EBLK, 256, 0, stream>>>(eidx, wsi + OFF_CNTN, wsi + OFF_CNTF, wsi + OFF_FLAGS);
  k_scan<<<2, 1024, 0, stream>>>(wsi + OFF_CNTN, wsi + OFF_STAN);
  k_fill<<<EBLK, 256, 0, stream>>>(eidx, wsi + OFF_STAN, wsi + OFF_STAF,
                                   wsi + OFF_OTHN, wsi + OFF_OTHF,
                                   posN, posF, wsi + OFF_FLAGS);
  k_proj<<<NBLK, 256, 0, stream>>>(feat, P, Fp_h);
  k_proj<<<NBLK, 256, 0, stream>>>(node, P, Np_h);
  k_ep<<<EBLK, 256, 0, stream>>>(eemb, P + 64*DD, bP, posN, posF, epN_h, epF_h);
  // gatherN overwrites the pos arrays (dead after k_ep)
  k_gather2<<<12500, 256, 0, stream>>>(wsi + OFF_STAN, wsi + OFF_CNTN,
                                       wsi + OFF_OTHN, epN_h, Fp_h, msgN);
  k_gather2<<<12500, 256, 0, stream>>>(wsi + OFF_STAF, wsi + OFF_CNTF,
                                       wsi + OFF_OTHF, epF_h, Np_h, msgF);
  // upd-feat first (overwrites Np region); then upd-node (overwrites Fp region)
  k_upd<<<NBLK, 256, 0, stream>>>(feat, msgF, wsi + OFF_CNTF, Q, bQ, W + 128*DD,
                                  out + (size_t)(ND + NE)*DD);
  k_upd<<<NBLK, 256, 0, stream>>>(node, msgN, wsi + OFF_CNTN, Q, bQ, W + 64*DD, out);
  // fused edge_out overwrites ep region
  k_eout<<<EBLK, 256, 0, stream>>>(eemb, eidx, W, bW,
                                   (const u16*)msgN, (const u16*)msgF,
                                   out + (size_t)ND*DD, wsi + OFF_FLAGS);
}